// Round 2
// baseline (553.957 us; speedup 1.0000x reference)
//
#include <hip/hip_runtime.h>
#include <hip/hip_bf16.h>
#include <math.h>

// SigmaMoE: T=4096 tokens, H=1024, I=512, E=16 experts, top-2, shared IS=1024.
// Inputs/outputs are FLOAT32 (per reference); internal GEMMs run bf16 MFMA.
#define H_DIM 1024
#define I_DIM 512
#define E_NUM 16
#define T_TOK 4096
#define IS_DIM 1024

typedef unsigned short u16;
typedef __attribute__((ext_vector_type(8))) short short8;   // 8 x bf16 MFMA frag
typedef __attribute__((ext_vector_type(4))) float floatx4;  // 4 x f32 MFMA acc

__device__ __forceinline__ float bf2f(u16 u) {
    union { unsigned int u; float f; } c; c.u = ((unsigned int)u) << 16; return c.f;
}
__device__ __forceinline__ u16 f2bf(float f) {
    union { float f; unsigned int u; } c; c.f = f;
    unsigned int r = (c.u + 0x7fffu + ((c.u >> 16) & 1u)) >> 16;
    return (u16)r;
}

// ---------------------------------------------------------------------------
// Weight convert+transpose: f32 K-major -> bf16 N-major (contiguous K per row),
// 64x64 tiles via LDS. 6912 blocks.
// ---------------------------------------------------------------------------
__global__ __launch_bounds__(256)
void k_transpose(const float* wg, const float* wu, const float* wd,
                 const float* sg, const float* su, const float* sd,
                 u16* wgt, u16* wut, u16* wdt, u16* sgt, u16* sut, u16* sdt)
{
    int bx = blockIdx.x;
    const float* src; u16* dst; int R, C, local;
    if (bx < 2048)      { src = wg; dst = wgt; R = 1024; C = 512;  local = bx; }
    else if (bx < 4096) { src = wu; dst = wut; R = 1024; C = 512;  local = bx - 2048; }
    else if (bx < 6144) { src = wd; dst = wdt; R = 512;  C = 1024; local = bx - 4096; }
    else if (bx < 6400) { src = sg; dst = sgt; R = 1024; C = 1024; local = bx - 6144; }
    else if (bx < 6656) { src = su; dst = sut; R = 1024; C = 1024; local = bx - 6400; }
    else                { src = sd; dst = sdt; R = 1024; C = 1024; local = bx - 6656; }
    int tpm = (R >> 6) * (C >> 6);
    int mat = local / tpm;
    int tl_ = local - mat * tpm;
    int tcn = C >> 6;
    int tr = tl_ / tcn, tc = tl_ - (tl_ / tcn) * tcn;
    src += (size_t)mat * R * C;
    dst += (size_t)mat * R * C;

    __shared__ u16 tile[64][65];
    int t = threadIdx.x;
    int r0 = t >> 2, c0 = (t & 3) * 16;        // each thread: row r0, 16 cols
    const float* sp = src + (size_t)(tr * 64 + r0) * C + tc * 64 + c0;
    #pragma unroll
    for (int j = 0; j < 16; j += 4) {
        float4 v = *(const float4*)(sp + j);
        tile[r0][c0 + j + 0] = f2bf(v.x);
        tile[r0][c0 + j + 1] = f2bf(v.y);
        tile[r0][c0 + j + 2] = f2bf(v.z);
        tile[r0][c0 + j + 3] = f2bf(v.w);
    }
    __syncthreads();
    int cW = t >> 2, rW = (t & 3) * 16;        // write col cW, rows rW..rW+15
    u16 tmp[16];
    #pragma unroll
    for (int j = 0; j < 16; ++j) tmp[j] = tile[rW + j][cW];
    u16* dp = dst + (size_t)(tc * 64 + cW) * R + tr * 64 + rW;
    *(uint4*)(dp)     = *(const uint4*)(tmp);
    *(uint4*)(dp + 8) = *(const uint4*)(tmp + 8);
}

// f32 -> bf16 copy of x (A-operand rows).
__global__ __launch_bounds__(256)
void k_xconv(const float* x, u16* xb)
{
    int i = blockIdx.x * 256 + threadIdx.x;    // float4 index
    float4 v = ((const float4*)x)[i];
    u16 o[4] = { f2bf(v.x), f2bf(v.y), f2bf(v.z), f2bf(v.w) };
    ((uint2*)xb)[i] = *(const uint2*)o;
}

// ---------------------------------------------------------------------------
// Router: softmax(x @ rw^T) top-2; normalized weights reduce to
// w1 = 1/(1+exp(s2-s1)). One wave per token. f32 inputs.
// ---------------------------------------------------------------------------
__global__ __launch_bounds__(256)
void k_router(const float* x, const float* rw, float* topkw, int* elist, int* cnt)
{
    int lane = threadIdx.x & 63;
    int wv = threadIdx.x >> 6;
    int t = blockIdx.x * 4 + wv;
    const float* xr = x + (size_t)t * H_DIM;
    float xv[16];
    #pragma unroll
    for (int j = 0; j < 16; ++j) xv[j] = xr[j * 64 + lane];
    float sc[E_NUM];
    #pragma unroll
    for (int e = 0; e < E_NUM; ++e) {
        const float* rr = rw + e * H_DIM;
        float s = 0.f;
        #pragma unroll
        for (int j = 0; j < 16; ++j) s += xv[j] * rr[j * 64 + lane];
        #pragma unroll
        for (int off = 32; off > 0; off >>= 1) s += __shfl_xor(s, off, 64);
        sc[e] = s;
    }
    if (lane == 0) {
        float b1 = -1e30f, b2 = -1e30f; int i1 = 0, i2 = 0;
        #pragma unroll
        for (int e = 0; e < E_NUM; ++e) {
            if (sc[e] > b1) { b2 = b1; i2 = i1; b1 = sc[e]; i1 = e; }
            else if (sc[e] > b2) { b2 = sc[e]; i2 = e; }
        }
        float w1 = 1.f / (1.f + __expf(b2 - b1));
        float w2 = 1.f - w1;
        topkw[t * 2]     = w1;
        topkw[t * 2 + 1] = w2;
        int p1 = atomicAdd(&cnt[i1], 1); elist[i1 * T_TOK + p1] = (t << 1);
        int p2 = atomicAdd(&cnt[i2], 1); elist[i2 * T_TOK + p2] = (t << 1) | 1;
    }
}

// Padded (to 64) exclusive prefix over counts -> act-buffer row bases.
__global__ void k_prefix(const int* cnt, int* base)
{
    if (threadIdx.x == 0) {
        int b = 0;
        for (int e = 0; e < E_NUM; ++e) { base[e] = b; b += ((cnt[e] + 63) >> 6) << 6; }
    }
}

// ---------------------------------------------------------------------------
// Grouped gate/up GEMM (routed). Block = (expert, 64-row m-tile, 64-col n-tile),
// BK=32, 4 waves, wave computes 16x64 of both gate and up.
// A rows gathered by token id (bf16 xb); act = silu(g)*u stored bf16.
// ---------------------------------------------------------------------------
__global__ __launch_bounds__(256)
void k_expert_gateup(const u16* xb, const u16* wgt, const u16* wut,
                     const int* elist, const int* cnt, const int* base, u16* act)
{
    int e = blockIdx.x >> 6;
    int mt = blockIdx.x & 63;
    int c = cnt[e];
    if (mt * 64 >= c) return;
    int nt = blockIdx.y;  // 0..7

    __shared__ u16 lA[64 * 40], lG[64 * 40], lU[64 * 40];
    int tid = threadIdx.x;
    int srow = tid >> 2, koff = (tid & 3) * 8;
    int p = mt * 64 + srow;
    int pc = p < c ? p : c - 1;               // clamp pad rows to a valid token
    int tok = elist[e * T_TOK + pc] >> 1;
    const u16* xr = xb  + (size_t)tok * H_DIM + koff;
    const u16* gr = wgt + ((size_t)e * I_DIM + nt * 64 + srow) * H_DIM + koff;
    const u16* ur = wut + ((size_t)e * I_DIM + nt * 64 + srow) * H_DIM + koff;
    uint4* sA = (uint4*)&lA[srow * 40 + koff];
    uint4* sG = (uint4*)&lG[srow * 40 + koff];
    uint4* sU = (uint4*)&lU[srow * 40 + koff];

    int lane = tid & 63, wv = tid >> 6;
    int m0 = wv * 16, quad = lane >> 4, l15 = lane & 15, kq = quad * 8;
    floatx4 zf = {0.f, 0.f, 0.f, 0.f};
    floatx4 accg[4], accu[4];
    #pragma unroll
    for (int i = 0; i < 4; ++i) { accg[i] = zf; accu[i] = zf; }

    for (int k0 = 0; k0 < H_DIM; k0 += 32) {
        uint4 va = *(const uint4*)(xr + k0);
        uint4 vg = *(const uint4*)(gr + k0);
        uint4 vu = *(const uint4*)(ur + k0);
        __syncthreads();
        *sA = va; *sG = vg; *sU = vu;
        __syncthreads();
        short8 af = *(const short8*)&lA[(m0 + l15) * 40 + kq];
        #pragma unroll
        for (int ct = 0; ct < 4; ++ct) {
            short8 bg = *(const short8*)&lG[(ct * 16 + l15) * 40 + kq];
            short8 bu = *(const short8*)&lU[(ct * 16 + l15) * 40 + kq];
            accg[ct] = __builtin_amdgcn_mfma_f32_16x16x32_bf16(af, bg, accg[ct], 0, 0, 0);
            accu[ct] = __builtin_amdgcn_mfma_f32_16x16x32_bf16(af, bu, accu[ct], 0, 0, 0);
        }
    }
    int abase = base[e] + mt * 64;
    #pragma unroll
    for (int ct = 0; ct < 4; ++ct) {
        #pragma unroll
        for (int r = 0; r < 4; ++r) {
            int row = m0 + quad * 4 + r;
            int col = nt * 64 + ct * 16 + l15;
            float g = accg[ct][r], u = accu[ct][r];
            float a = g / (1.f + __expf(-g)) * u;   // silu(g)*u
            act[(size_t)(abase + row) * I_DIM + col] = f2bf(a);
        }
    }
}

// ---------------------------------------------------------------------------
// Grouped down GEMM (routed). Y rows scattered to slot buffers (bf16, scaled
// by routing weight). Each token has exactly one slot-0 and one slot-1 entry,
// so y0/y1 are fully written -> no init, no atomics.
// ---------------------------------------------------------------------------
__global__ __launch_bounds__(256)
void k_expert_down(const u16* act, const u16* wdt, const int* elist,
                   const int* cnt, const int* base, const float* topkw,
                   u16* y0, u16* y1)
{
    int e = blockIdx.x >> 6;
    int mt = blockIdx.x & 63;
    int c = cnt[e];
    if (mt * 64 >= c) return;
    int nt = blockIdx.y;  // 0..15

    __shared__ u16 lA[64 * 40], lB[64 * 40];
    int tid = threadIdx.x;
    int srow = tid >> 2, koff = (tid & 3) * 8;
    const u16* ar = act + (size_t)(base[e] + mt * 64 + srow) * I_DIM + koff;
    const u16* br = wdt + ((size_t)e * H_DIM + nt * 64 + srow) * I_DIM + koff;
    uint4* sA = (uint4*)&lA[srow * 40 + koff];
    uint4* sB = (uint4*)&lB[srow * 40 + koff];

    int lane = tid & 63, wv = tid >> 6;
    int m0 = wv * 16, quad = lane >> 4, l15 = lane & 15, kq = quad * 8;
    floatx4 zf = {0.f, 0.f, 0.f, 0.f};
    floatx4 acc[4];
    #pragma unroll
    for (int i = 0; i < 4; ++i) acc[i] = zf;

    for (int k0 = 0; k0 < I_DIM; k0 += 32) {
        uint4 va = *(const uint4*)(ar + k0);
        uint4 vb = *(const uint4*)(br + k0);
        __syncthreads();
        *sA = va; *sB = vb;
        __syncthreads();
        short8 af = *(const short8*)&lA[(m0 + l15) * 40 + kq];
        #pragma unroll
        for (int ct = 0; ct < 4; ++ct) {
            short8 bf = *(const short8*)&lB[(ct * 16 + l15) * 40 + kq];
            acc[ct] = __builtin_amdgcn_mfma_f32_16x16x32_bf16(af, bf, acc[ct], 0, 0, 0);
        }
    }
    #pragma unroll
    for (int ct = 0; ct < 4; ++ct) {
        #pragma unroll
        for (int r = 0; r < 4; ++r) {
            int row = m0 + quad * 4 + r;
            int p = mt * 64 + row;
            if (p < c) {
                int ent = elist[e * T_TOK + p];
                int t = ent >> 1, s = ent & 1;
                float w = topkw[t * 2 + s];
                u16* yb = s ? y1 : y0;
                yb[(size_t)t * H_DIM + nt * 64 + ct * 16 + l15] = f2bf(w * acc[ct][r]);
            }
        }
    }
}

// ---------------------------------------------------------------------------
// Shared expert gate/up: dense 4096x1024(x1024) GEMM pair -> sact (bf16).
// ---------------------------------------------------------------------------
__global__ __launch_bounds__(256)
void k_shared_gateup(const u16* xb, const u16* sgt, const u16* sut, u16* sact)
{
    int mt = blockIdx.x;  // 0..63
    int nt = blockIdx.y;  // 0..15
    __shared__ u16 lA[64 * 40], lG[64 * 40], lU[64 * 40];
    int tid = threadIdx.x;
    int srow = tid >> 2, koff = (tid & 3) * 8;
    const u16* xr = xb  + (size_t)(mt * 64 + srow) * H_DIM + koff;
    const u16* gr = sgt + (size_t)(nt * 64 + srow) * H_DIM + koff;
    const u16* ur = sut + (size_t)(nt * 64 + srow) * H_DIM + koff;
    uint4* sA = (uint4*)&lA[srow * 40 + koff];
    uint4* sG = (uint4*)&lG[srow * 40 + koff];
    uint4* sU = (uint4*)&lU[srow * 40 + koff];

    int lane = tid & 63, wv = tid >> 6;
    int m0 = wv * 16, quad = lane >> 4, l15 = lane & 15, kq = quad * 8;
    floatx4 zf = {0.f, 0.f, 0.f, 0.f};
    floatx4 accg[4], accu[4];
    #pragma unroll
    for (int i = 0; i < 4; ++i) { accg[i] = zf; accu[i] = zf; }

    for (int k0 = 0; k0 < H_DIM; k0 += 32) {
        uint4 va = *(const uint4*)(xr + k0);
        uint4 vg = *(const uint4*)(gr + k0);
        uint4 vu = *(const uint4*)(ur + k0);
        __syncthreads();
        *sA = va; *sG = vg; *sU = vu;
        __syncthreads();
        short8 af = *(const short8*)&lA[(m0 + l15) * 40 + kq];
        #pragma unroll
        for (int ct = 0; ct < 4; ++ct) {
            short8 bg = *(const short8*)&lG[(ct * 16 + l15) * 40 + kq];
            short8 bu = *(const short8*)&lU[(ct * 16 + l15) * 40 + kq];
            accg[ct] = __builtin_amdgcn_mfma_f32_16x16x32_bf16(af, bg, accg[ct], 0, 0, 0);
            accu[ct] = __builtin_amdgcn_mfma_f32_16x16x32_bf16(af, bu, accu[ct], 0, 0, 0);
        }
    }
    #pragma unroll
    for (int ct = 0; ct < 4; ++ct) {
        #pragma unroll
        for (int r = 0; r < 4; ++r) {
            int row = mt * 64 + m0 + quad * 4 + r;
            int col = nt * 64 + ct * 16 + l15;
            float g = accg[ct][r], u = accu[ct][r];
            float a = g / (1.f + __expf(-g)) * u;
            sact[(size_t)row * IS_DIM + col] = f2bf(a);
        }
    }
}

// ---------------------------------------------------------------------------
// Shared down GEMM + final combine: out = f32(sact@sd + y0 + y1).
// ---------------------------------------------------------------------------
__global__ __launch_bounds__(256)
void k_shared_down(const u16* sact, const u16* sdt, const u16* y0, const u16* y1,
                   float* out)
{
    int mt = blockIdx.x;  // 0..63
    int nt = blockIdx.y;  // 0..15
    __shared__ u16 lA[64 * 40], lB[64 * 40];
    int tid = threadIdx.x;
    int srow = tid >> 2, koff = (tid & 3) * 8;
    const u16* ar = sact + (size_t)(mt * 64 + srow) * IS_DIM + koff;
    const u16* br = sdt  + (size_t)(nt * 64 + srow) * IS_DIM + koff;
    uint4* sA = (uint4*)&lA[srow * 40 + koff];
    uint4* sB = (uint4*)&lB[srow * 40 + koff];

    int lane = tid & 63, wv = tid >> 6;
    int m0 = wv * 16, quad = lane >> 4, l15 = lane & 15, kq = quad * 8;
    floatx4 zf = {0.f, 0.f, 0.f, 0.f};
    floatx4 acc[4];
    #pragma unroll
    for (int i = 0; i < 4; ++i) acc[i] = zf;

    for (int k0 = 0; k0 < IS_DIM; k0 += 32) {
        uint4 va = *(const uint4*)(ar + k0);
        uint4 vb = *(const uint4*)(br + k0);
        __syncthreads();
        *sA = va; *sB = vb;
        __syncthreads();
        short8 af = *(const short8*)&lA[(m0 + l15) * 40 + kq];
        #pragma unroll
        for (int ct = 0; ct < 4; ++ct) {
            short8 bf = *(const short8*)&lB[(ct * 16 + l15) * 40 + kq];
            acc[ct] = __builtin_amdgcn_mfma_f32_16x16x32_bf16(af, bf, acc[ct], 0, 0, 0);
        }
    }
    #pragma unroll
    for (int ct = 0; ct < 4; ++ct) {
        #pragma unroll
        for (int r = 0; r < 4; ++r) {
            int row = mt * 64 + m0 + quad * 4 + r;
            int col = nt * 64 + ct * 16 + l15;
            float v = acc[ct][r] + bf2f(y0[(size_t)row * H_DIM + col])
                                 + bf2f(y1[(size_t)row * H_DIM + col]);
            out[(size_t)row * H_DIM + col] = v;
        }
    }
}

// ---------------------------------------------------------------------------
extern "C" void kernel_launch(void* const* d_in, const int* in_sizes, int n_in,
                              void* d_out, int out_size, void* d_ws, size_t ws_size,
                              hipStream_t stream)
{
    const float* x  = (const float*)d_in[0];
    const float* rw = (const float*)d_in[1];
    const float* wg = (const float*)d_in[2];
    const float* wu = (const float*)d_in[3];
    const float* wd = (const float*)d_in[4];
    const float* sg = (const float*)d_in[5];
    const float* su = (const float*)d_in[6];
    const float* sd = (const float*)d_in[7];
    float* out = (float*)d_out;

    char* ws = (char*)d_ws;
    const size_t MB = 1024ull * 1024ull;
    u16* wgt  = (u16*)(ws);            // [E][I][H] bf16  16 MB
    u16* wut  = (u16*)(ws + 16 * MB);  // [E][I][H]       16 MB
    u16* wdt  = (u16*)(ws + 32 * MB);  // [E][H][I]       16 MB
    u16* sgt  = (u16*)(ws + 48 * MB);  // [IS][H]          2 MB
    u16* sut  = (u16*)(ws + 50 * MB);  // [IS][H]          2 MB
    u16* sdt  = (u16*)(ws + 52 * MB);  // [H][IS]          2 MB
    u16* xb   = (u16*)(ws + 54 * MB);  // [T][H] bf16      8 MB
    u16* act  = (u16*)(ws + 62 * MB);  // [<=10240][I]    10 MB (padded rows)
    u16* sact = (u16*)(ws + 72 * MB);  // [T][IS]          8 MB
    u16* y0   = (u16*)(ws + 80 * MB);  // [T][H] slot0     8 MB
    u16* y1   = (u16*)(ws + 88 * MB);  // [T][H] slot1     8 MB
    float* topkw = (float*)(ws + 96 * MB);          // [T][2]
    int* elist   = (int*)(ws + 96 * MB + 64 * 1024);// [E][T]
    int* cnt     = (int*)(ws + 97 * MB);            // [E]
    int* base    = (int*)(ws + 97 * MB + 256);      // [E]

    hipMemsetAsync(cnt, 0, E_NUM * sizeof(int), stream);
    k_transpose<<<6912, 256, 0, stream>>>(wg, wu, wd, sg, su, sd,
                                          wgt, wut, wdt, sgt, sut, sdt);
    k_xconv<<<T_TOK * H_DIM / 4 / 256, 256, 0, stream>>>(x, xb);
    k_router<<<T_TOK / 4, 256, 0, stream>>>(x, rw, topkw, elist, cnt);
    k_prefix<<<1, 64, 0, stream>>>(cnt, base);
    k_expert_gateup<<<dim3(E_NUM * 64, I_DIM / 64), 256, 0, stream>>>(
        xb, wgt, wut, elist, cnt, base, act);
    k_expert_down<<<dim3(E_NUM * 64, H_DIM / 64), 256, 0, stream>>>(
        act, wdt, elist, cnt, base, topkw, y0, y1);
    k_shared_gateup<<<dim3(T_TOK / 64, IS_DIM / 64), 256, 0, stream>>>(
        xb, sgt, sut, sact);
    k_shared_down<<<dim3(T_TOK / 64, H_DIM / 64), 256, 0, stream>>>(
        sact, sdt, y0, y1, out);
}